// Round 1
// baseline (508.796 us; speedup 1.0000x reference)
//
#include <hip/hip_runtime.h>
#include <hip/hip_bf16.h>
#include <stdint.h>

// Problem constants
#define B_   32
#define N_   480
#define DIM_ 1024
#define H_   16
#define D_   64
#define M_   (B_*N_)   // 15360
#define BH_  (B_*H_)   // 512

typedef __bf16 bf16;
typedef __bf16 bf16x4 __attribute__((ext_vector_type(4)));
typedef __bf16 bf16x8 __attribute__((ext_vector_type(8)));
typedef float  f32x4  __attribute__((ext_vector_type(4)));

// async global->LDS, 16B per lane; LDS dest = wave-uniform base + lane*16 (CK pattern)
__device__ __forceinline__ void gld_lds16(const void* g, void* l) {
    using GP = const __attribute__((address_space(1))) unsigned int*;
    using LP = __attribute__((address_space(3))) unsigned int*;
    __builtin_amdgcn_global_load_lds((GP)(uintptr_t)g, (LP)(unsigned int)(uintptr_t)l, 16, 0, 0);
}

// ---------------- fp32 -> bf16 convert (vectorized x4) ----------------
__global__ void cvt4(const float* __restrict__ in, bf16* __restrict__ out, int n4) {
    int i = blockIdx.x * 256 + threadIdx.x;
    if (i >= n4) return;
    float4 v = ((const float4*)in)[i];
    bf16x4 o = { (bf16)v.x, (bf16)v.y, (bf16)v.z, (bf16)v.w };
    ((bf16x4*)out)[i] = o;
}

// ---------------- QKV projection GEMM ----------------
// C[m, gn] = sum_k A[m,k] * Wcat[gn,k];  M=15360, N=3072, K=1024.
// Epilogue scatter: Q,K -> [bh][n][d]; V -> [bh][d][n] (transposed).
__global__ __launch_bounds__(256) void gemm_qkv(const bf16* __restrict__ A, const bf16* __restrict__ Bw,
                                                bf16* __restrict__ Qp, bf16* __restrict__ Kp,
                                                bf16* __restrict__ Vt) {
    __shared__ bf16 As[128*32];
    __shared__ bf16 Bs[128*32];
    const int tid  = threadIdx.x;
    const int lane = tid & 63;
    const int wid  = tid >> 6;
    const int wm   = wid & 1, wn = wid >> 1;
    const int m0   = blockIdx.y * 128;
    const int n0   = blockIdx.x * 128;
    const int lm   = lane & 15, lq = lane >> 4;

    // staging: each wave stages 16 rows per pass, 2 passes each for A and B
    const int srow = wid*16 + (lane >> 2);
    const int scol = (lane & 3) * 8;
    const int aOff0 = (m0 + srow) * 1024 + scol;
    const int aOff1 = (m0 + 64 + srow) * 1024 + scol;
    const int bOff0 = (n0 + srow) * 1024 + scol;
    const int bOff1 = (n0 + 64 + srow) * 1024 + scol;
    bf16* AsW0 = &As[(wid*16)*32];
    bf16* AsW1 = &As[(64 + wid*16)*32];
    bf16* BsW0 = &Bs[(wid*16)*32];
    bf16* BsW1 = &Bs[(64 + wid*16)*32];

    f32x4 acc[4][4] = {};
    for (int k0 = 0; k0 < 1024; k0 += 32) {
        gld_lds16(A  + aOff0 + k0, AsW0);
        gld_lds16(A  + aOff1 + k0, AsW1);
        gld_lds16(Bw + bOff0 + k0, BsW0);
        gld_lds16(Bw + bOff1 + k0, BsW1);
        __syncthreads();  // drains vmcnt -> LDS valid
        bf16x8 af[4], bfr[4];
#pragma unroll
        for (int m = 0; m < 4; ++m) af[m]  = *(const bf16x8*)&As[(wm*64 + m*16 + lm)*32 + lq*8];
#pragma unroll
        for (int n = 0; n < 4; ++n) bfr[n] = *(const bf16x8*)&Bs[(wn*64 + n*16 + lm)*32 + lq*8];
#pragma unroll
        for (int m = 0; m < 4; ++m)
#pragma unroll
            for (int n = 0; n < 4; ++n)
                acc[m][n] = __builtin_amdgcn_mfma_f32_16x16x32_bf16(af[m], bfr[n], acc[m][n], 0, 0, 0);
        __syncthreads();  // all reads done before next stage overwrites
    }

    // epilogue scatter (C layout: col=lane&15, row=(lane>>4)*4+reg)
    const int part = n0 >> 10;  // 0=Q,1=K,2=V (uniform per block: 128 | 1024)
#pragma unroll
    for (int m = 0; m < 4; ++m) {
#pragma unroll
        for (int n = 0; n < 4; ++n) {
#pragma unroll
            for (int r = 0; r < 4; ++r) {
                int gm = m0 + wm*64 + m*16 + lq*4 + r;
                int gn = n0 + wn*64 + n*16 + lm;
                bf16 v = (bf16)acc[m][n][r];
                int b  = gm / 480;
                int nn = gm - b*480;
                int rem = gn & 1023;
                int h = rem >> 6, d = rem & 63;
                int bh = b*16 + h;
                if (part == 0)      Qp[(bh*480 + nn)*64 + d] = v;
                else if (part == 1) Kp[(bh*480 + nn)*64 + d] = v;
                else                Vt[(bh*64 + d)*480 + nn] = v;
            }
        }
    }
}

// ---------------- fused attention (flash-style, online softmax) ----------------
// grid (10 q-tiles, 512 bh), 192 threads = 3 waves x 16 q-rows. K-tiles of 48.
__global__ __launch_bounds__(192) void attn(const bf16* __restrict__ Qp, const bf16* __restrict__ Kp,
                                            const bf16* __restrict__ Vt, const float* __restrict__ pe,
                                            bf16* __restrict__ O) {
    __shared__ bf16 Ks[48*64];
    __shared__ bf16 Vs[64*48 + 32];   // +32 guard (reads past last row, multiplied by P-pad zeros)
    __shared__ bf16 Ps[3*16*64];      // per-wave P tile (16 x 64, cols 48..63 always zero)

    const int tid  = threadIdx.x;
    const int lane = tid & 63, wid = tid >> 6;
    const int bh   = blockIdx.y;
    const int b    = bh >> 4, h = bh & 15;
    const int q0   = blockIdx.x * 48;
    const int lm   = lane & 15, lq = lane >> 4;
    const int qbase = bh * (N_ * 64);

    // zero own Ps region (wave-local) and the Vs guard zone
    {
        bf16x8 z = {};
        bf16* base = &Ps[wid * 1024];
        *(bf16x8*)&base[lane * 8] = z;
        *(bf16x8*)&base[512 + lane * 8] = z;
        if (tid < 4) *(bf16x8*)&Vs[64*48 + tid*8] = z;
    }

    // Q fragments (A-operand layout: m=lane&15, k=lq*8+j), kept in registers
    bf16x8 qa[2];
#pragma unroll
    for (int ks = 0; ks < 2; ++ks)
        qa[ks] = *(const bf16x8*)&Qp[qbase + (q0 + wid*16 + lm)*64 + ks*32 + lq*8];

    float m_i[4], l_i[4];
    f32x4 o_acc[4] = {};
#pragma unroll
    for (int r = 0; r < 4; ++r) { m_i[r] = -1e30f; l_i[r] = 0.f; }

    for (int kt = 0; kt < 10; ++kt) {
        __syncthreads();  // prior iter's LDS reads done (also covers init stores)
        // stage Ks: 48 rows x 64 d (384 x 16B chunks)
#pragma unroll
        for (int p = 0; p < 2; ++p) {
            int c = p*192 + tid;
            int row = c >> 3, off = (c & 7) * 8;
            *(uint4*)&Ks[row*64 + off] = *(const uint4*)&Kp[qbase + (kt*48 + row)*64 + off];
        }
        // stage Vs: 64 rows (d) x 48 cols (keys), stride 48
#pragma unroll
        for (int p = 0; p < 2; ++p) {
            int c = p*192 + tid;
            int row = c / 6, off = (c % 6) * 8;
            *(uint4*)&Vs[row*48 + off] = *(const uint4*)&Vt[qbase + row*480 + kt*48 + off];
        }
        __syncthreads();

        // S = Q K^T (3 col-frags of 16 keys, 2 k-steps over d=64)
        f32x4 s[3] = {};
#pragma unroll
        for (int cf = 0; cf < 3; ++cf)
#pragma unroll
            for (int ks = 0; ks < 2; ++ks) {
                bf16x8 kb = *(const bf16x8*)&Ks[(cf*16 + lm)*64 + ks*32 + lq*8];
                s[cf] = __builtin_amdgcn_mfma_f32_16x16x32_bf16(qa[ks], kb, s[cf], 0, 0, 0);
            }

        // logits = s*scale + pe  (C layout: row=lq*4+r, col=lm)
        float sv[3][4];
        const int qr0 = q0 + wid*16 + lq*4;
#pragma unroll
        for (int cf = 0; cf < 3; ++cf)
#pragma unroll
            for (int r = 0; r < 4; ++r)
                sv[cf][r] = s[cf][r] * 0.125f + pe[(qr0 + r)*480 + kt*48 + cf*16 + lm];

        // online softmax update
        float mnew[4], alpha[4];
#pragma unroll
        for (int r = 0; r < 4; ++r) {
            float t = fmaxf(fmaxf(sv[0][r], sv[1][r]), sv[2][r]);
            t = fmaxf(t, __shfl_xor(t, 1));
            t = fmaxf(t, __shfl_xor(t, 2));
            t = fmaxf(t, __shfl_xor(t, 4));
            t = fmaxf(t, __shfl_xor(t, 8));
            mnew[r] = fmaxf(m_i[r], t);
            alpha[r] = __expf(m_i[r] - mnew[r]);
            m_i[r] = mnew[r];
        }
#pragma unroll
        for (int r = 0; r < 4; ++r) {
            float rs = 0.f;
#pragma unroll
            for (int cf = 0; cf < 3; ++cf) {
                float p = __expf(sv[cf][r] - mnew[r]);
                sv[cf][r] = p;
                rs += p;
            }
            rs += __shfl_xor(rs, 1);
            rs += __shfl_xor(rs, 2);
            rs += __shfl_xor(rs, 4);
            rs += __shfl_xor(rs, 8);
            l_i[r] = l_i[r] * alpha[r] + rs;
#pragma unroll
            for (int nf = 0; nf < 4; ++nf) o_acc[nf][r] *= alpha[r];
        }

        // P: C-layout -> LDS -> A-layout (wave-local; compiler orders via lgkmcnt)
        bf16* pbase = &Ps[wid * 1024];
#pragma unroll
        for (int cf = 0; cf < 3; ++cf)
#pragma unroll
            for (int r = 0; r < 4; ++r)
                pbase[(lq*4 + r)*64 + cf*16 + lm] = (bf16)sv[cf][r];

        // O += P V  (k padded 48->64; P cols 48..63 are zero)
#pragma unroll
        for (int ks = 0; ks < 2; ++ks) {
            bf16x8 pa = *(const bf16x8*)&pbase[lm*64 + ks*32 + lq*8];
#pragma unroll
            for (int nf = 0; nf < 4; ++nf) {
                bf16x8 vb = *(const bf16x8*)&Vs[(nf*16 + lm)*48 + ks*32 + lq*8];
                o_acc[nf] = __builtin_amdgcn_mfma_f32_16x16x32_bf16(pa, vb, o_acc[nf], 0, 0, 0);
            }
        }
    }

    // epilogue: O /= l, store to [b, n, h*64+d] (row-major M x 1024)
#pragma unroll
    for (int nf = 0; nf < 4; ++nf)
#pragma unroll
        for (int r = 0; r < 4; ++r) {
            int qrow = q0 + wid*16 + lq*4 + r;
            float v = o_acc[nf][r] / l_i[r];
            O[(b*480 + qrow)*1024 + h*64 + nf*16 + lm] = (bf16)v;
        }
}

// ---------------- output projection GEMM + bias ----------------
__global__ __launch_bounds__(256) void gemm_out(const bf16* __restrict__ A, const bf16* __restrict__ Bw,
                                                const float* __restrict__ bo, float* __restrict__ out) {
    __shared__ bf16 As[128*32];
    __shared__ bf16 Bs[128*32];
    const int tid  = threadIdx.x;
    const int lane = tid & 63;
    const int wid  = tid >> 6;
    const int wm   = wid & 1, wn = wid >> 1;
    const int m0   = blockIdx.y * 128;
    const int n0   = blockIdx.x * 128;
    const int lm   = lane & 15, lq = lane >> 4;

    const int srow = wid*16 + (lane >> 2);
    const int scol = (lane & 3) * 8;
    const int aOff0 = (m0 + srow) * 1024 + scol;
    const int aOff1 = (m0 + 64 + srow) * 1024 + scol;
    const int bOff0 = (n0 + srow) * 1024 + scol;
    const int bOff1 = (n0 + 64 + srow) * 1024 + scol;
    bf16* AsW0 = &As[(wid*16)*32];
    bf16* AsW1 = &As[(64 + wid*16)*32];
    bf16* BsW0 = &Bs[(wid*16)*32];
    bf16* BsW1 = &Bs[(64 + wid*16)*32];

    f32x4 acc[4][4] = {};
    for (int k0 = 0; k0 < 1024; k0 += 32) {
        gld_lds16(A  + aOff0 + k0, AsW0);
        gld_lds16(A  + aOff1 + k0, AsW1);
        gld_lds16(Bw + bOff0 + k0, BsW0);
        gld_lds16(Bw + bOff1 + k0, BsW1);
        __syncthreads();
        bf16x8 af[4], bfr[4];
#pragma unroll
        for (int m = 0; m < 4; ++m) af[m]  = *(const bf16x8*)&As[(wm*64 + m*16 + lm)*32 + lq*8];
#pragma unroll
        for (int n = 0; n < 4; ++n) bfr[n] = *(const bf16x8*)&Bs[(wn*64 + n*16 + lm)*32 + lq*8];
#pragma unroll
        for (int m = 0; m < 4; ++m)
#pragma unroll
            for (int n = 0; n < 4; ++n)
                acc[m][n] = __builtin_amdgcn_mfma_f32_16x16x32_bf16(af[m], bfr[n], acc[m][n], 0, 0, 0);
        __syncthreads();
    }
#pragma unroll
    for (int m = 0; m < 4; ++m)
#pragma unroll
        for (int n = 0; n < 4; ++n)
#pragma unroll
            for (int r = 0; r < 4; ++r) {
                int gm = m0 + wm*64 + m*16 + lq*4 + r;
                int gn = n0 + wn*64 + n*16 + lm;
                out[gm*1024 + gn] = acc[m][n][r] + bo[gn];
            }
}

// ---------------- launcher ----------------
extern "C" void kernel_launch(void* const* d_in, const int* in_sizes, int n_in,
                              void* d_out, int out_size, void* d_ws, size_t ws_size,
                              hipStream_t stream) {
    const float* q  = (const float*)d_in[0];
    const float* Wq = (const float*)d_in[1];
    const float* Wk = (const float*)d_in[2];
    const float* Wv = (const float*)d_in[3];
    const float* pe = (const float*)d_in[4];
    const float* Wo = (const float*)d_in[5];
    const float* bo = (const float*)d_in[6];
    float* out = (float*)d_out;

    char* ws = (char*)d_ws;
    // workspace layout (bytes), 128 MB total
    bf16* Abf  = (bf16*)(ws);                         // q bf16 (M x 1024); reused later as attn O buffer
    bf16* Wcat = (bf16*)(ws + 31457280);              // 3072 x 1024
    bf16* Wob  = (bf16*)(ws + 31457280 + 6291456);    // 1024 x 1024
    bf16* Qp   = (bf16*)(ws + 39845888);              // [bh][n][d]
    bf16* Kp   = (bf16*)(ws + 71303168);              // [bh][n][d]
    bf16* Vt   = (bf16*)(ws + 102760448);             // [bh][d][n]

    // converts
    cvt4<<<(M_*DIM_/4 + 255)/256, 256, 0, stream>>>(q,  Abf, M_*DIM_/4);
    cvt4<<<(DIM_*DIM_/4 + 255)/256, 256, 0, stream>>>(Wq, Wcat,                 DIM_*DIM_/4);
    cvt4<<<(DIM_*DIM_/4 + 255)/256, 256, 0, stream>>>(Wk, Wcat + DIM_*DIM_,     DIM_*DIM_/4);
    cvt4<<<(DIM_*DIM_/4 + 255)/256, 256, 0, stream>>>(Wv, Wcat + 2*DIM_*DIM_,   DIM_*DIM_/4);
    cvt4<<<(DIM_*DIM_/4 + 255)/256, 256, 0, stream>>>(Wo, Wob, DIM_*DIM_/4);

    // QKV projection: M=15360, N=3072
    gemm_qkv<<<dim3(24, 120), 256, 0, stream>>>(Abf, Wcat, Qp, Kp, Vt);

    // attention: writes O into Abf region (q-bf16 no longer needed)
    attn<<<dim3(10, 512), 192, 0, stream>>>(Qp, Kp, Vt, pe, Abf);

    // output projection: M=15360, N=1024
    gemm_out<<<dim3(8, 120), 256, 0, stream>>>(Abf, Wob, bo, out);
}

// Round 2
// 472.729 us; speedup vs baseline: 1.0763x; 1.0763x over previous
//
#include <hip/hip_runtime.h>
#include <hip/hip_bf16.h>
#include <stdint.h>

// Problem constants
#define B_   32
#define N_   480
#define DIM_ 1024
#define H_   16
#define D_   64
#define M_   (B_*N_)   // 15360
#define BH_  (B_*H_)   // 512

typedef __bf16 bf16;
typedef __bf16 bf16x4 __attribute__((ext_vector_type(4)));
typedef __bf16 bf16x8 __attribute__((ext_vector_type(8)));
typedef short  short4v __attribute__((ext_vector_type(4)));
typedef float  f32x4  __attribute__((ext_vector_type(4)));

// async global->LDS, 16B per lane; LDS dest = wave-uniform base + lane*16
__device__ __forceinline__ void gld_lds16(const void* g, void* l) {
    using GP = const __attribute__((address_space(1))) unsigned int*;
    using LP = __attribute__((address_space(3))) unsigned int*;
    __builtin_amdgcn_global_load_lds((GP)(uintptr_t)g, (LP)(unsigned int)(uintptr_t)l, 16, 0, 0);
}

// ---------------- fp32 -> bf16 converts ----------------
__global__ void cvt4(const float* __restrict__ in, bf16* __restrict__ out, int n4) {
    int i = blockIdx.x * 256 + threadIdx.x;
    if (i >= n4) return;
    float4 v = ((const float4*)in)[i];
    bf16x4 o = { (bf16)v.x, (bf16)v.y, (bf16)v.z, (bf16)v.w };
    ((bf16x4*)out)[i] = o;
}

// all four weight matrices in one launch (grid.y selects)
__global__ void cvtW(const float* __restrict__ Wq, const float* __restrict__ Wk,
                     const float* __restrict__ Wv, const float* __restrict__ Wo,
                     bf16* __restrict__ Wcat, bf16* __restrict__ Wob) {
    int i = blockIdx.x * 256 + threadIdx.x;            // 0 .. 262143 (1M/4)
    const float* src; bf16* dst;
    switch (blockIdx.y) {
        case 0: src = Wq; dst = Wcat;                break;
        case 1: src = Wk; dst = Wcat + DIM_*DIM_;    break;
        case 2: src = Wv; dst = Wcat + 2*DIM_*DIM_;  break;
        default: src = Wo; dst = Wob;                break;
    }
    float4 v = ((const float4*)src)[i];
    bf16x4 o = { (bf16)v.x, (bf16)v.y, (bf16)v.z, (bf16)v.w };
    ((bf16x4*)dst)[i] = o;
}

// ---------------- QKV projection GEMM ----------------
// C[m, gn] = sum_k A[m,k] * Wcat[gn,k];  M=15360, N=3072, K=1024.
// Epilogue scatter: Q,K -> [bh][n][d]; V -> [bh][d][n] (transposed).
__global__ __launch_bounds__(256) void gemm_qkv(const bf16* __restrict__ A, const bf16* __restrict__ Bw,
                                                bf16* __restrict__ Qp, bf16* __restrict__ Kp,
                                                bf16* __restrict__ Vt) {
    __shared__ bf16 As[128*32];
    __shared__ bf16 Bs[128*32];
    const int tid  = threadIdx.x;
    const int lane = tid & 63;
    const int wid  = tid >> 6;
    const int wm   = wid & 1, wn = wid >> 1;
    const int m0   = blockIdx.y * 128;
    const int n0   = blockIdx.x * 128;
    const int lm   = lane & 15, lq = lane >> 4;

    const int srow = wid*16 + (lane >> 2);
    const int scol = (lane & 3) * 8;
    const int aOff0 = (m0 + srow) * 1024 + scol;
    const int aOff1 = (m0 + 64 + srow) * 1024 + scol;
    const int bOff0 = (n0 + srow) * 1024 + scol;
    const int bOff1 = (n0 + 64 + srow) * 1024 + scol;
    bf16* AsW0 = &As[(wid*16)*32];
    bf16* AsW1 = &As[(64 + wid*16)*32];
    bf16* BsW0 = &Bs[(wid*16)*32];
    bf16* BsW1 = &Bs[(64 + wid*16)*32];

    f32x4 acc[4][4] = {};
    for (int k0 = 0; k0 < 1024; k0 += 32) {
        gld_lds16(A  + aOff0 + k0, AsW0);
        gld_lds16(A  + aOff1 + k0, AsW1);
        gld_lds16(Bw + bOff0 + k0, BsW0);
        gld_lds16(Bw + bOff1 + k0, BsW1);
        __syncthreads();
        bf16x8 af[4], bfr[4];
#pragma unroll
        for (int m = 0; m < 4; ++m) af[m]  = *(const bf16x8*)&As[(wm*64 + m*16 + lm)*32 + lq*8];
#pragma unroll
        for (int n = 0; n < 4; ++n) bfr[n] = *(const bf16x8*)&Bs[(wn*64 + n*16 + lm)*32 + lq*8];
#pragma unroll
        for (int m = 0; m < 4; ++m)
#pragma unroll
            for (int n = 0; n < 4; ++n)
                acc[m][n] = __builtin_amdgcn_mfma_f32_16x16x32_bf16(af[m], bfr[n], acc[m][n], 0, 0, 0);
        __syncthreads();
    }

    // epilogue scatter (C layout: col=lane&15, row=(lane>>4)*4+reg)
    const int part = n0 >> 10;  // 0=Q,1=K,2=V (uniform per block)
    int hh[4], dd[4];
#pragma unroll
    for (int n = 0; n < 4; ++n) {
        int gn = n0 + wn*64 + n*16 + lm;
        int rem = gn & 1023;
        hh[n] = rem >> 6; dd[n] = rem & 63;
    }
#pragma unroll
    for (int m = 0; m < 4; ++m) {
#pragma unroll
        for (int r = 0; r < 4; ++r) {
            int gm = m0 + wm*64 + m*16 + lq*4 + r;
            int b  = gm / 480;
            int nn = gm - b*480;
#pragma unroll
            for (int n = 0; n < 4; ++n) {
                bf16 v = (bf16)acc[m][n][r];
                int bh = b*16 + hh[n];
                if (part == 0)      Qp[(bh*480 + nn)*64 + dd[n]] = v;
                else if (part == 1) Kp[(bh*480 + nn)*64 + dd[n]] = v;
                else                Vt[(bh*64 + dd[n])*480 + nn] = v;
            }
        }
    }
}

// ---------------- fused attention v2 ----------------
// S^T = K Q^T orientation; no max-subtraction (logits bounded ~7); K-tile 96.
// P^T exits the S^T MFMA directly in 16x16x16 B-operand layout -> no P LDS trip.
// grid (10 q-tiles, 512 bh), 192 threads = 3 waves x 16 q-rows each.
#define KT 96
#define KS_LD 72    // Ks row stride (bf16 elems): 144 B -> 2-way banks (free)
#define VS_LD 104   // Vs row stride: 208 B -> 2-way banks (free)
__global__ __launch_bounds__(192) void attn(const bf16* __restrict__ Qp, const bf16* __restrict__ Kp,
                                            const bf16* __restrict__ Vt, const float* __restrict__ pe,
                                            bf16* __restrict__ O) {
    __shared__ bf16 Ks[KT*KS_LD];     // [key][d]
    __shared__ bf16 Vs[64*VS_LD];     // [d][key]
    const int tid  = threadIdx.x;
    const int lane = tid & 63, wid = tid >> 6;
    const int bh   = blockIdx.y;
    const int b    = bh >> 4, h = bh & 15;
    const int q0   = blockIdx.x * 48;
    const int lm   = lane & 15, lq = lane >> 4;
    const int qbase = bh * (N_ * 64);

    // Q fragments as B-operand (n=q=lm, k=d=lq*8+j), kept in registers
    bf16x8 qb[2];
#pragma unroll
    for (int ks = 0; ks < 2; ++ks)
        qb[ks] = *(const bf16x8*)&Qp[qbase + (q0 + wid*16 + lm)*64 + ks*32 + lq*8];
    const float* peRow = pe + (q0 + wid*16 + lm)*480;

    f32x4 ot[4] = {};      // O^T accum: m=d (4 frags), n=q
    float lsum = 0.f;      // per-lane partial of softmax denom for q=lm

    for (int kt = 0; kt < 5; ++kt) {
        __syncthreads();   // prior iter's LDS reads done
        // stage Ks: 96 keys x 64 d (768 x 16B chunks)
#pragma unroll
        for (int p = 0; p < 4; ++p) {
            int c = p*192 + tid;
            int row = c >> 3, of = (c & 7) * 8;
            *(uint4*)&Ks[row*KS_LD + of] = *(const uint4*)&Kp[qbase + (kt*KT + row)*64 + of];
        }
        // stage Vs: 64 d-rows x 96 keys (768 x 16B chunks)
#pragma unroll
        for (int p = 0; p < 4; ++p) {
            int c = p*192 + tid;
            int row = c / 12, of = (c % 12) * 8;
            *(uint4*)&Vs[row*VS_LD + of] = *(const uint4*)&Vt[qbase + row*480 + kt*KT + of];
        }
        __syncthreads();

        // S^T = K Q^T; P^T = exp(scale*S^T + pe) packed as 16x16x16 B-frags
        short4v pb[6];
#pragma unroll
        for (int mf = 0; mf < 6; ++mf) {
            f32x4 s = {};
#pragma unroll
            for (int ks = 0; ks < 2; ++ks) {
                bf16x8 ka = *(const bf16x8*)&Ks[(mf*16 + lm)*KS_LD + ks*32 + lq*8];
                s = __builtin_amdgcn_mfma_f32_16x16x32_bf16(ka, qb[ks], s, 0, 0, 0);
            }
            bf16x4 pv;
#pragma unroll
            for (int r = 0; r < 4; ++r) {
                float e = __expf(s[r] * 0.125f + peRow[kt*KT + mf*16 + lq*4 + r]);
                lsum += e;
                pv[r] = (bf16)e;
            }
            pb[mf] = __builtin_bit_cast(short4v, pv);
        }

        // O^T += V^T P^T via 16x16x16 (A = V frags straight from Vs rows)
#pragma unroll
        for (int df = 0; df < 4; ++df)
#pragma unroll
            for (int mf = 0; mf < 6; ++mf) {
                short4v va = *(const short4v*)&Vs[(df*16 + lm)*VS_LD + mf*16 + lq*4];
                ot[df] = __builtin_amdgcn_mfma_f32_16x16x16bf16_1k(va, pb[mf], ot[df], 0, 0, 0);
            }
    }

    // softmax denom: reduce partials over the 4 lane-groups holding q=lm
    lsum += __shfl_xor(lsum, 16);
    lsum += __shfl_xor(lsum, 32);
    float rl = 1.f / lsum;

    // transpose O^T -> O via LDS (reuse Ks region), then coalesced store
    __syncthreads();
    bf16* Os = Ks;  // [48 q][72 stride], cols 0..63 = d
#pragma unroll
    for (int df = 0; df < 4; ++df)
#pragma unroll
        for (int r = 0; r < 4; ++r)
            Os[(wid*16 + lm)*KS_LD + df*16 + lq*4 + r] = (bf16)(ot[df][r] * rl);
    __syncthreads();
    {
        int ql = tid >> 2, d0 = (tid & 3) * 16;
        uint4 u0 = *(const uint4*)&Os[ql*KS_LD + d0];
        uint4 u1 = *(const uint4*)&Os[ql*KS_LD + d0 + 8];
        bf16* orow = &O[(b*480 + q0 + ql)*1024 + h*64 + d0];
        *(uint4*)&orow[0] = u0;
        *(uint4*)&orow[8] = u1;
    }
}

// ---------------- output projection GEMM + bias ----------------
__global__ __launch_bounds__(256) void gemm_out(const bf16* __restrict__ A, const bf16* __restrict__ Bw,
                                                const float* __restrict__ bo, float* __restrict__ out) {
    __shared__ bf16 As[128*32];
    __shared__ bf16 Bs[128*32];
    const int tid  = threadIdx.x;
    const int lane = tid & 63;
    const int wid  = tid >> 6;
    const int wm   = wid & 1, wn = wid >> 1;
    const int m0   = blockIdx.y * 128;
    const int n0   = blockIdx.x * 128;
    const int lm   = lane & 15, lq = lane >> 4;

    const int srow = wid*16 + (lane >> 2);
    const int scol = (lane & 3) * 8;
    const int aOff0 = (m0 + srow) * 1024 + scol;
    const int aOff1 = (m0 + 64 + srow) * 1024 + scol;
    const int bOff0 = (n0 + srow) * 1024 + scol;
    const int bOff1 = (n0 + 64 + srow) * 1024 + scol;
    bf16* AsW0 = &As[(wid*16)*32];
    bf16* AsW1 = &As[(64 + wid*16)*32];
    bf16* BsW0 = &Bs[(wid*16)*32];
    bf16* BsW1 = &Bs[(64 + wid*16)*32];

    f32x4 acc[4][4] = {};
    for (int k0 = 0; k0 < 1024; k0 += 32) {
        gld_lds16(A  + aOff0 + k0, AsW0);
        gld_lds16(A  + aOff1 + k0, AsW1);
        gld_lds16(Bw + bOff0 + k0, BsW0);
        gld_lds16(Bw + bOff1 + k0, BsW1);
        __syncthreads();
        bf16x8 af[4], bfr[4];
#pragma unroll
        for (int m = 0; m < 4; ++m) af[m]  = *(const bf16x8*)&As[(wm*64 + m*16 + lm)*32 + lq*8];
#pragma unroll
        for (int n = 0; n < 4; ++n) bfr[n] = *(const bf16x8*)&Bs[(wn*64 + n*16 + lm)*32 + lq*8];
#pragma unroll
        for (int m = 0; m < 4; ++m)
#pragma unroll
            for (int n = 0; n < 4; ++n)
                acc[m][n] = __builtin_amdgcn_mfma_f32_16x16x32_bf16(af[m], bfr[n], acc[m][n], 0, 0, 0);
        __syncthreads();
    }
#pragma unroll
    for (int m = 0; m < 4; ++m)
#pragma unroll
        for (int n = 0; n < 4; ++n)
#pragma unroll
            for (int r = 0; r < 4; ++r) {
                int gm = m0 + wm*64 + m*16 + lq*4 + r;
                int gn = n0 + wn*64 + n*16 + lm;
                out[gm*1024 + gn] = acc[m][n][r] + bo[gn];
            }
}

// ---------------- launcher ----------------
extern "C" void kernel_launch(void* const* d_in, const int* in_sizes, int n_in,
                              void* d_out, int out_size, void* d_ws, size_t ws_size,
                              hipStream_t stream) {
    const float* q  = (const float*)d_in[0];
    const float* Wq = (const float*)d_in[1];
    const float* Wk = (const float*)d_in[2];
    const float* Wv = (const float*)d_in[3];
    const float* pe = (const float*)d_in[4];
    const float* Wo = (const float*)d_in[5];
    const float* bo = (const float*)d_in[6];
    float* out = (float*)d_out;

    char* ws = (char*)d_ws;
    bf16* Abf  = (bf16*)(ws);                         // q bf16 (M x 1024); reused as attn O buffer
    bf16* Wcat = (bf16*)(ws + 31457280);              // 3072 x 1024
    bf16* Wob  = (bf16*)(ws + 31457280 + 6291456);    // 1024 x 1024
    bf16* Qp   = (bf16*)(ws + 39845888);              // [bh][n][d]
    bf16* Kp   = (bf16*)(ws + 71303168);              // [bh][n][d]
    bf16* Vt   = (bf16*)(ws + 102760448);             // [bh][d][n]

    cvt4<<<(M_*DIM_/4 + 255)/256, 256, 0, stream>>>(q, Abf, M_*DIM_/4);
    cvtW<<<dim3(DIM_*DIM_/4/256, 4), 256, 0, stream>>>(Wq, Wk, Wv, Wo, Wcat, Wob);

    gemm_qkv<<<dim3(24, 120), 256, 0, stream>>>(Abf, Wcat, Qp, Kp, Vt);
    attn<<<dim3(10, 512), 192, 0, stream>>>(Qp, Kp, Vt, pe, Abf);
    gemm_out<<<dim3(8, 120), 256, 0, stream>>>(Abf, Wob, bo, out);
}

// Round 3
// 414.074 us; speedup vs baseline: 1.2288x; 1.1417x over previous
//
#include <hip/hip_runtime.h>
#include <hip/hip_bf16.h>
#include <stdint.h>

// Problem constants
#define B_   32
#define N_   480
#define DIM_ 1024
#define H_   16
#define D_   64
#define M_   (B_*N_)   // 15360
#define BH_  (B_*H_)   // 512

typedef __bf16 bf16;
typedef __bf16 bf16x4 __attribute__((ext_vector_type(4)));
typedef __bf16 bf16x8 __attribute__((ext_vector_type(8)));
typedef short  short4v __attribute__((ext_vector_type(4)));
typedef float  f32x4  __attribute__((ext_vector_type(4)));

// async global->LDS, 16B per lane; LDS dest = wave-uniform base + lane*16
__device__ __forceinline__ void gld_lds16(const void* g, void* l) {
    using GP = const __attribute__((address_space(1))) unsigned int*;
    using LP = __attribute__((address_space(3))) unsigned int*;
    __builtin_amdgcn_global_load_lds((GP)(uintptr_t)g, (LP)(unsigned int)(uintptr_t)l, 16, 0, 0);
}

// ---------------- fp32 -> bf16 converts ----------------
__global__ void cvt4(const float* __restrict__ in, bf16* __restrict__ out, int n4) {
    int i = blockIdx.x * 256 + threadIdx.x;
    if (i >= n4) return;
    float4 v = ((const float4*)in)[i];
    bf16x4 o = { (bf16)v.x, (bf16)v.y, (bf16)v.z, (bf16)v.w };
    ((bf16x4*)out)[i] = o;
}

__global__ void cvtW(const float* __restrict__ Wq, const float* __restrict__ Wk,
                     const float* __restrict__ Wv, const float* __restrict__ Wo,
                     bf16* __restrict__ Wcat, bf16* __restrict__ Wob) {
    int i = blockIdx.x * 256 + threadIdx.x;
    const float* src; bf16* dst;
    switch (blockIdx.y) {
        case 0: src = Wq; dst = Wcat;                break;
        case 1: src = Wk; dst = Wcat + DIM_*DIM_;    break;
        case 2: src = Wv; dst = Wcat + 2*DIM_*DIM_;  break;
        default: src = Wo; dst = Wob;                break;
    }
    float4 v = ((const float4*)src)[i];
    bf16x4 o = { (bf16)v.x, (bf16)v.y, (bf16)v.z, (bf16)v.w };
    ((bf16x4*)dst)[i] = o;
}

// ======== shared GEMM core: 128x128 tile, BK=64, XOR-swizzled LDS ========
// LDS layout: row r (128B = 8 chunks of 16B); logical chunk c stored at
// physical slot c^(r&7). global_load_lds writes lane->slot `lane` of an
// 8-row group, so lane fetches global chunk (lane&7)^((lane>>3)&7) of row
// (lane>>3). ds_read_b128 fragment reads then hit all 32 banks 2-way (free).
#define GEMM_PRE()                                                            \
    const int tid  = threadIdx.x;                                             \
    const int lane = tid & 63;                                                \
    const int wid  = tid >> 6;                                                \
    const int wm   = wid & 1, wn = wid >> 1;                                  \
    const int m0   = blockIdx.y * 128;                                        \
    const int n0   = blockIdx.x * 128;                                        \
    const int lm   = lane & 15, lq = lane >> 4;                               \
    const int aLane = (lane >> 3) * 1024 + (((lane & 7) ^ (lane >> 3)) & 7) * 8; \
    const bf16* Asrc = A  + (m0 + wid*32) * 1024 + aLane;                     \
    const bf16* Bsrc = Bw + (n0 + wid*32) * 1024 + aLane;                     \
    bf16* AsDst = As + (wid*32)*64;                                           \
    bf16* BsDst = Bs + (wid*32)*64;                                           \
    int rowA[4], rowB[4];                                                     \
    _Pragma("unroll") for (int m = 0; m < 4; ++m) rowA[m] = (wm*64 + m*16 + lm)*64; \
    _Pragma("unroll") for (int n = 0; n < 4; ++n) rowB[n] = (wn*64 + n*16 + lm)*64; \
    const int sw = lm & 7;                                                    \
    int phys[2];                                                              \
    phys[0] = ((lq)     ^ sw) * 8;                                            \
    phys[1] = ((4 + lq) ^ sw) * 8;

#define GEMM_KLOOP(FIRST, SECOND)                                             \
    for (int k0 = 0; k0 < 1024; k0 += 64) {                                   \
        _Pragma("unroll") for (int j = 0; j < 4; ++j) {                       \
            gld_lds16(Asrc + k0 + j*8192, AsDst + j*512);                     \
            gld_lds16(Bsrc + k0 + j*8192, BsDst + j*512);                     \
        }                                                                     \
        __syncthreads();                                                      \
        _Pragma("unroll") for (int ks = 0; ks < 2; ++ks) {                    \
            bf16x8 af[4], bfr[4];                                             \
            _Pragma("unroll") for (int m = 0; m < 4; ++m)                     \
                af[m]  = *(const bf16x8*)&As[rowA[m] + phys[ks]];             \
            _Pragma("unroll") for (int n = 0; n < 4; ++n)                     \
                bfr[n] = *(const bf16x8*)&Bs[rowB[n] + phys[ks]];             \
            _Pragma("unroll") for (int m = 0; m < 4; ++m)                     \
                _Pragma("unroll") for (int n = 0; n < 4; ++n)                 \
                    acc[m][n] = __builtin_amdgcn_mfma_f32_16x16x32_bf16(      \
                        FIRST, SECOND, acc[m][n], 0, 0, 0);                   \
        }                                                                     \
        __syncthreads();                                                      \
    }

// ---------------- QKV projection GEMM ----------------
// C[m,gn] = sum_k A[m,k]*Wcat[gn,k]; Q,K -> [bh][n][d]; V -> [bh][d][n].
// V blocks use swapped MFMA operands (compute C^T) so the transposed store
// is lane-contiguous along n.
__global__ __launch_bounds__(256) void gemm_qkv(const bf16* __restrict__ A, const bf16* __restrict__ Bw,
                                                bf16* __restrict__ Qp, bf16* __restrict__ Kp,
                                                bf16* __restrict__ Vt) {
    __shared__ bf16 As[128*64];
    __shared__ bf16 Bs[128*64];
    GEMM_PRE();
    const int part = n0 >> 10;  // 0=Q,1=K,2=V (block-uniform)
    f32x4 acc[4][4] = {};

    if (part != 2) {
        GEMM_KLOOP(af[m], bfr[n]);
        // C layout: col(gn)=lm, row(gm)=lq*4+r
        bf16* dst = (part == 0) ? Qp : Kp;
        int hh[4], dd[4];
#pragma unroll
        for (int n = 0; n < 4; ++n) {
            int rem = (n0 + wn*64 + n*16 + lm) & 1023;
            hh[n] = rem >> 6; dd[n] = rem & 63;
        }
#pragma unroll
        for (int m = 0; m < 4; ++m) {
#pragma unroll
            for (int r = 0; r < 4; ++r) {
                int gm = m0 + wm*64 + m*16 + lq*4 + r;
                int b  = gm / 480;
                int nn = gm - b*480;
#pragma unroll
                for (int n = 0; n < 4; ++n)
                    dst[((b*16 + hh[n])*480 + nn)*64 + dd[n]] = (bf16)acc[m][n][r];
            }
        }
    } else {
        GEMM_KLOOP(bfr[n], af[m]);
        // C^T layout: col(gm)=lm, row(gn)=lq*4+r -> stores contiguous in nn
#pragma unroll
        for (int m = 0; m < 4; ++m) {
            int gmBase = m0 + wm*64 + m*16;      // lane-uniform; 480%16==0 -> b uniform
            int b  = gmBase / 480;
            int nn = gmBase - b*480 + lm;
#pragma unroll
            for (int n = 0; n < 4; ++n)
#pragma unroll
                for (int r = 0; r < 4; ++r) {
                    int rem = (n0 + wn*64 + n*16 + lq*4 + r) & 1023;
                    int h = rem >> 6, d = rem & 63;
                    Vt[((b*16 + h)*64 + d)*480 + nn] = (bf16)acc[m][n][r];
                }
        }
    }
}

// ---------------- fused attention v3 ----------------
// S^T = K Q^T; no max-subtraction (logits bounded ~7); K-tile 96; q-tile 80
// (5 waves) so K/V are restaged 6x instead of 10x per bh.
#define KT 96
#define KS_LD 72    // 144B rows -> 2-way banks (free)
#define VS_LD 104   // 208B rows -> 2-way banks (free)
__global__ __launch_bounds__(320) void attn(const bf16* __restrict__ Qp, const bf16* __restrict__ Kp,
                                            const bf16* __restrict__ Vt, const float* __restrict__ pe,
                                            bf16* __restrict__ O) {
    __shared__ bf16 Ks[KT*KS_LD];     // [key][d]
    __shared__ bf16 Vs[64*VS_LD];     // [d][key]
    const int tid  = threadIdx.x;
    const int lane = tid & 63, wid = tid >> 6;
    const int bh   = blockIdx.y;
    const int b    = bh >> 4, h = bh & 15;
    const int qblk = blockIdx.x * 80;
    const int lm   = lane & 15, lq = lane >> 4;
    const int qbase = bh * (N_ * 64);

    // Q fragments as B-operand (n=q=lm, k=d=lq*8+j)
    bf16x8 qb[2];
#pragma unroll
    for (int ks = 0; ks < 2; ++ks)
        qb[ks] = *(const bf16x8*)&Qp[qbase + (qblk + wid*16 + lm)*64 + ks*32 + lq*8];
    const float* peRow = pe + (qblk + wid*16 + lm)*480;

    f32x4 ot[4] = {};      // O^T accum: m=d (4 frags), n=q
    float lsum = 0.f;

    for (int kt = 0; kt < 5; ++kt) {
        __syncthreads();
        for (int c = tid; c < 768; c += 320) {
            int row = c >> 3, of = (c & 7) * 8;
            *(uint4*)&Ks[row*KS_LD + of] = *(const uint4*)&Kp[qbase + (kt*KT + row)*64 + of];
        }
        for (int c = tid; c < 768; c += 320) {
            int row = c / 12, of = (c % 12) * 8;
            *(uint4*)&Vs[row*VS_LD + of] = *(const uint4*)&Vt[qbase + row*480 + kt*KT + of];
        }
        __syncthreads();

        // S^T = K Q^T; P^T = exp(scale*S^T + pe) packed as 16x16x16 B-frags
        short4v pb[6];
#pragma unroll
        for (int mf = 0; mf < 6; ++mf) {
            f32x4 s = {};
#pragma unroll
            for (int ks = 0; ks < 2; ++ks) {
                bf16x8 ka = *(const bf16x8*)&Ks[(mf*16 + lm)*KS_LD + ks*32 + lq*8];
                s = __builtin_amdgcn_mfma_f32_16x16x32_bf16(ka, qb[ks], s, 0, 0, 0);
            }
            bf16x4 pv;
#pragma unroll
            for (int r = 0; r < 4; ++r) {
                float e = __expf(s[r] * 0.125f + peRow[kt*KT + mf*16 + lq*4 + r]);
                lsum += e;
                pv[r] = (bf16)e;
            }
            pb[mf] = __builtin_bit_cast(short4v, pv);
        }

        // O^T += V^T P^T via 16x16x16 (A = V frags straight from Vs rows)
#pragma unroll
        for (int df = 0; df < 4; ++df)
#pragma unroll
            for (int mf = 0; mf < 6; ++mf) {
                short4v va = *(const short4v*)&Vs[(df*16 + lm)*VS_LD + mf*16 + lq*4];
                ot[df] = __builtin_amdgcn_mfma_f32_16x16x16bf16_1k(va, pb[mf], ot[df], 0, 0, 0);
            }
    }

    // softmax denom across the 4 lane-groups holding q=lm
    lsum += __shfl_xor(lsum, 16);
    lsum += __shfl_xor(lsum, 32);
    float rl = 1.f / lsum;

    // transpose O^T -> O via LDS (reuse Ks region), coalesced 16B stores
    __syncthreads();
    bf16* Os = Ks;  // [80 q][KS_LD]
#pragma unroll
    for (int df = 0; df < 4; ++df)
#pragma unroll
        for (int r = 0; r < 4; ++r)
            Os[(wid*16 + lm)*KS_LD + df*16 + lq*4 + r] = (bf16)(ot[df][r] * rl);
    __syncthreads();
    for (int c = tid; c < 640; c += 320) {
        int row = c >> 3, d0 = (c & 7) * 8;
        uint4 u = *(const uint4*)&Os[row*KS_LD + d0];
        *(uint4*)&O[(b*480 + qblk + row)*1024 + h*64 + d0] = u;
    }
}

// ---------------- output projection GEMM + bias ----------------
__global__ __launch_bounds__(256) void gemm_out(const bf16* __restrict__ A, const bf16* __restrict__ Bw,
                                                const float* __restrict__ bo, float* __restrict__ out) {
    __shared__ bf16 As[128*64];
    __shared__ bf16 Bs[128*64];
    GEMM_PRE();
    f32x4 acc[4][4] = {};
    GEMM_KLOOP(af[m], bfr[n]);
#pragma unroll
    for (int m = 0; m < 4; ++m)
#pragma unroll
        for (int n = 0; n < 4; ++n)
#pragma unroll
            for (int r = 0; r < 4; ++r) {
                int gm = m0 + wm*64 + m*16 + lq*4 + r;
                int gn = n0 + wn*64 + n*16 + lm;
                out[gm*1024 + gn] = acc[m][n][r] + bo[gn];
            }
}

// ---------------- launcher ----------------
extern "C" void kernel_launch(void* const* d_in, const int* in_sizes, int n_in,
                              void* d_out, int out_size, void* d_ws, size_t ws_size,
                              hipStream_t stream) {
    const float* q  = (const float*)d_in[0];
    const float* Wq = (const float*)d_in[1];
    const float* Wk = (const float*)d_in[2];
    const float* Wv = (const float*)d_in[3];
    const float* pe = (const float*)d_in[4];
    const float* Wo = (const float*)d_in[5];
    const float* bo = (const float*)d_in[6];
    float* out = (float*)d_out;

    char* ws = (char*)d_ws;
    bf16* Abf  = (bf16*)(ws);                         // q bf16 (M x 1024); reused as attn O buffer
    bf16* Wcat = (bf16*)(ws + 31457280);              // 3072 x 1024
    bf16* Wob  = (bf16*)(ws + 31457280 + 6291456);    // 1024 x 1024
    bf16* Qp   = (bf16*)(ws + 39845888);              // [bh][n][d]
    bf16* Kp   = (bf16*)(ws + 71303168);              // [bh][n][d]
    bf16* Vt   = (bf16*)(ws + 102760448);             // [bh][d][n]

    cvt4<<<(M_*DIM_/4 + 255)/256, 256, 0, stream>>>(q, Abf, M_*DIM_/4);
    cvtW<<<dim3(DIM_*DIM_/4/256, 4), 256, 0, stream>>>(Wq, Wk, Wv, Wo, Wcat, Wob);

    gemm_qkv<<<dim3(24, 120), 256, 0, stream>>>(Abf, Wcat, Qp, Kp, Vt);
    attn<<<dim3(6, 512), 320, 0, stream>>>(Qp, Kp, Vt, pe, Abf);
    gemm_out<<<dim3(8, 120), 256, 0, stream>>>(Abf, Wob, bo, out);
}